// Round 6
// baseline (271.451 us; speedup 1.0000x reference)
//
#include <hip/hip_runtime.h>
#include <hip/hip_bf16.h>

typedef __attribute__((ext_vector_type(8))) short short8;
typedef __attribute__((ext_vector_type(4))) float f32x4;

#define NROWS 8192
#define DIM   1024
#define NCH   256
#define CHROW 32        // rows per chunk
#define XROW  1088      // xb row stride (1024 cols + aug col 1024=1.0 + zero pad)
#define MROW  1152      // Mt row stride (cols = k-dim, padded)
#define KTG   1088      // tgemm K extent

#define BM 128
#define BN 128
#define BK 64

__device__ __forceinline__ float bf2f(unsigned short u) {
    union { unsigned int i; float f; } v; v.i = ((unsigned int)u) << 16; return v.f;
}
__device__ __forceinline__ unsigned short f2bf(float f) {
    union { float f; unsigned int i; } v; v.f = f;
    unsigned int r = v.i + 0x7fffu + ((v.i >> 16) & 1u);
    return (unsigned short)(r >> 16);
}
__device__ __forceinline__ void gload_lds16(const unsigned short* g, unsigned short* l) {
    __builtin_amdgcn_global_load_lds(
        (const __attribute__((address_space(1))) void*)g,
        (__attribute__((address_space(3))) void*)l, 16, 0, 0);
}

// ---------------------------------------------------------------- K1: prep
// [0,512)     : 64x64 transpose tiles fp32->bf16 (Wq->WqTb, Wk->WkTb)
// [512,520)   : WqTb augmentation rows 1024..1151 (row 1024 = bq, rest 0)
// [520,1032)  : per-chunk column sums of x -> csums (chunk x col-half)
// [1032,1048) : zero rsum(8192 f) + g2(8192 f) (contiguous)
// [1048,1052) : u[a] = sum_h Wq[h][a]*bk[h]  (fp32)
// [1052]      : c = bq.bk ; zero cnt[64]
__global__ __launch_bounds__(256) void prep(
    const float* __restrict__ Wq, const float* __restrict__ bq,
    const float* __restrict__ Wk, const float* __restrict__ bk,
    const float* __restrict__ x,
    unsigned short* __restrict__ WqTb, unsigned short* __restrict__ WkTb,
    float* __restrict__ csums, float* __restrict__ rsum,
    float* __restrict__ u, float* __restrict__ c_slot, int* __restrict__ cnt)
{
    __shared__ float sTf[64 * 65];
    const int bid = blockIdx.x, t = threadIdx.x;
    if (bid < 512) {
        const int mat = bid >> 8, t16 = bid & 255;
        const int h0 = (t16 >> 4) * 64, a0 = (t16 & 15) * 64;
        const float* src = mat ? Wk : Wq;
        unsigned short* dst = mat ? WkTb : WqTb;
        #pragma unroll
        for (int i = 0; i < 4; ++i) {
            int g = i * 256 + t;
            int row = g >> 4, c4 = (g & 15) * 4;
            float4 v = *(const float4*)(src + (size_t)(h0 + row) * DIM + a0 + c4);
            sTf[row * 65 + c4 + 0] = v.x; sTf[row * 65 + c4 + 1] = v.y;
            sTf[row * 65 + c4 + 2] = v.z; sTf[row * 65 + c4 + 3] = v.w;
        }
        __syncthreads();
        #pragma unroll
        for (int i = 0; i < 4; ++i) {
            int g = i * 256 + t;
            int arow = g >> 4, h4 = (g & 15) * 4;
            ushort4 o;
            o.x = f2bf(sTf[(h4 + 0) * 65 + arow]);
            o.y = f2bf(sTf[(h4 + 1) * 65 + arow]);
            o.z = f2bf(sTf[(h4 + 2) * 65 + arow]);
            o.w = f2bf(sTf[(h4 + 3) * 65 + arow]);
            *(ushort4*)(dst + (size_t)(a0 + arow) * DIM + h0 + h4) = o;
        }
    } else if (bid < 520) {
        const int seg = bid - 512;
        const int r0 = 1024 + seg * 16;
        #pragma unroll
        for (int i = 0; i < 16; ++i) {
            int g = i * 256 + t;
            int row = r0 + (g >> 8), c4 = (g & 255) * 4;
            ushort4 o;
            if (row == 1024) {
                o.x = f2bf(bq[c4 + 0]); o.y = f2bf(bq[c4 + 1]);
                o.z = f2bf(bq[c4 + 2]); o.w = f2bf(bq[c4 + 3]);
            } else { o.x = o.y = o.z = o.w = 0; }
            *(ushort4*)(WqTb + (size_t)row * DIM + c4) = o;
        }
    } else if (bid < 1032) {
        const int s = bid - 520, ch = s >> 1, half = s & 1;
        const int col = half * 512 + t * 2;
        float s0 = 0.f, s1 = 0.f;
        #pragma unroll
        for (int r = 0; r < CHROW; ++r) {
            float2 v = *(const float2*)(x + (size_t)(ch * CHROW + r) * DIM + col);
            s0 += v.x; s1 += v.y;
        }
        float2 o; o.x = s0; o.y = s1;
        *(float2*)&csums[(size_t)ch * DIM + col] = o;
    } else if (bid < 1048) {
        const int idx = bid - 1032;             // zero rsum+g2 (16384 floats)
        f32x4 z = (f32x4)0.0f;
        *(f32x4*)&rsum[(idx * 256 + t) * 4] = z;
    } else if (bid < 1052) {
        const int a = (bid - 1048) * 256 + t;
        float s = 0.f;
        #pragma unroll 8
        for (int h = 0; h < DIM; ++h) s += Wq[(size_t)h * DIM + a] * bk[h];
        u[a] = s;
    } else {
        float s = 0.f;
        for (int h = t; h < DIM; h += 256) s += bq[h] * bk[h];
        #pragma unroll
        for (int sh = 32; sh >= 1; sh >>= 1) s += __shfl_xor(s, sh, 64);
        __shared__ float red[4];
        if ((t & 63) == 0) red[t >> 6] = s;
        __syncthreads();
        if (t == 0) c_slot[0] = red[0] + red[1] + red[2] + red[3];
        if (t < 64) cnt[t] = 0;
    }
}

// ---------------------------------------------------------------- K2: scan + g2-dot + mgemm
// [0,512)   : per-chunk scan: self-computed exclusive prefix over csums; writes
//             xb (bf16 + aug col), P (bf16), atomicAdd g2[row] += x_row.u (partial)
// [512,584) : mgemm — Mt[n][k] = sum_h WkT[n][h]*WqTaug[k][h]  (1024 x 1152, K=1024)
__global__ __launch_bounds__(256) void scan_mgemm(
    const float* __restrict__ x, const float* __restrict__ csums,
    const float* __restrict__ u,
    unsigned short* __restrict__ xb, unsigned short* __restrict__ P,
    float* __restrict__ g2,
    const unsigned short* __restrict__ WkTb, const unsigned short* __restrict__ WqTb,
    unsigned short* __restrict__ Mt)
{
    __shared__ __align__(16) char smem[2 * BM * BK * 2];   // 32 KB, dual-use
    const int t = threadIdx.x;
    if (blockIdx.x < 512) {
        const int s = blockIdx.x, ch = s >> 1, half = s & 1;
        const int col = half * 512 + t * 2;
        // self-computed exclusive prefix of chunk sums (csums stays raw)
        float2 run; run.x = 0.f; run.y = 0.f;
        #pragma unroll 8
        for (int c2 = 0; c2 < ch; ++c2) {
            float2 v = *(const float2*)&csums[(size_t)c2 * DIM + col];
            run.x += v.x; run.y += v.y;
        }
        const float u0 = u[col], u1 = u[col + 1];
        float part[CHROW];
        #pragma unroll
        for (int r = 0; r < CHROW; ++r) {
            size_t row = (size_t)ch * CHROW + r;
            float2 xv = *(const float2*)(x + row * DIM + col);
            ushort2 pb; pb.x = f2bf(run.x); pb.y = f2bf(run.y);
            *(ushort2*)(P + row * DIM + col) = pb;
            ushort2 xo; xo.x = f2bf(xv.x); xo.y = f2bf(xv.y);
            *(ushort2*)(xb + row * XROW + col) = xo;
            part[r] = xv.x * u0 + xv.y * u1;
            run.x += xv.x; run.y += xv.y;
        }
        if (half == 1) {      // aug cols 1024..1087
            int r = t >> 3, cg = (t & 7) * 8;
            size_t row = (size_t)ch * CHROW + r;
            ushort4 z0, z1; z1.x = z1.y = z1.z = z1.w = 0; z0 = z1;
            if (cg == 0) z0.x = 0x3F80;   // col 1024 = 1.0
            *(ushort4*)(xb + row * XROW + 1024 + cg) = z0;
            *(ushort4*)(xb + row * XROW + 1024 + cg + 4) = z1;
        }
        // g2 partial reduction: 32 rows x 256 threads
        float* sP = (float*)smem;
        #pragma unroll
        for (int r = 0; r < CHROW; ++r) sP[r * 256 + t] = part[r];
        __syncthreads();
        const int wave = t >> 6, lane = t & 63;
        #pragma unroll
        for (int r8 = 0; r8 < 8; ++r8) {
            int r = wave * 8 + r8;
            float v = sP[r * 256 + lane]       + sP[r * 256 + 64 + lane]
                    + sP[r * 256 + 128 + lane] + sP[r * 256 + 192 + lane];
            #pragma unroll
            for (int sh = 32; sh >= 1; sh >>= 1) v += __shfl_xor(v, sh, 64);
            if (lane == 0) atomicAdd(&g2[ch * CHROW + r], v);
        }
    } else {
        unsigned short* sA = (unsigned short*)smem;
        unsigned short* sB = (unsigned short*)smem + BM * BK;
        const int s = blockIdx.x - 512;            // 0..71
        const int bx = s & 7, by = s >> 3;         // bx: n-dim (1024), by: k-dim (1152)
        const int wave = t >> 6, lane = t & 63;
        const int quad = lane >> 4, l16 = lane & 15;
        const int m0 = bx * BM, n0 = by * BN;
        const int wm = (wave >> 1) * 64, wn = (wave & 1) * 64;
        const int rsel = lane >> 3, csel = (lane & 7) * 8;

        f32x4 acc[4][4];
        #pragma unroll
        for (int i = 0; i < 4; ++i)
            #pragma unroll
            for (int j = 0; j < 4; ++j) acc[i][j] = (f32x4)0.0f;

        for (int k0 = 0; k0 < DIM; k0 += BK) {
            __syncthreads();
            #pragma unroll
            for (int j = 0; j < 4; ++j) {
                const int row = wave * 32 + j * 8;
                gload_lds16(WkTb + (size_t)(m0 + row + rsel) * DIM + k0 + csel, &sA[row * BK]);
                gload_lds16(WqTb + (size_t)(n0 + row + rsel) * DIM + k0 + csel, &sB[row * BK]);
            }
            __syncthreads();
            #pragma unroll
            for (int ks = 0; ks < 2; ++ks) {
                const int kc = ks * 32 + quad * 8;
                short8 af[4], bfr[4];
                #pragma unroll
                for (int tt = 0; tt < 4; ++tt)
                    af[tt] = *(const short8*)&sA[(wm + tt * 16 + l16) * BK + kc];
                #pragma unroll
                for (int tt = 0; tt < 4; ++tt)
                    bfr[tt] = *(const short8*)&sB[(wn + tt * 16 + l16) * BK + kc];
                #pragma unroll
                for (int mt = 0; mt < 4; ++mt)
                    #pragma unroll
                    for (int nt = 0; nt < 4; ++nt)
                        acc[mt][nt] = __builtin_amdgcn_mfma_f32_16x16x32_bf16(
                            af[mt], bfr[nt], acc[mt][nt], 0, 0, 0);
            }
        }
        #pragma unroll
        for (int nt = 0; nt < 4; ++nt) {
            int n = n0 + wn + nt * 16 + l16;
            #pragma unroll
            for (int mt = 0; mt < 4; ++mt)
                #pragma unroll
                for (int r = 0; r < 4; ++r) {
                    int m = m0 + wm + mt * 16 + quad * 4 + r;
                    Mt[(size_t)m * MROW + n] = f2bf(acc[mt][nt][r]);
                }
        }
    }
}

// ---------------------------------------------------------------- K3: tgemm + dot-reduce + last-block writeout
// T[i][n] = sum_k xb[i][k]*Mt[n][k] (never materialized);
// atomicAdd rsum[i] += sum_n T[i][n]*P[i][n]; last finisher per row-group
// writes out[i][:] = rsum[i] + i*(g2[i]+c).  grid (64, 8, 2) split-K.
__global__ __launch_bounds__(256) void tgemm_red(
    const unsigned short* __restrict__ A,   // xb 8192 x XROW
    const unsigned short* __restrict__ B,   // Mt 1024 x MROW
    const unsigned short* __restrict__ P,   // 8192 x 1024
    float* __restrict__ rsum, const float* __restrict__ g2,
    const float* __restrict__ c_slot, int* __restrict__ cnt,
    float* __restrict__ out)
{
    __shared__ __align__(16) char smem[2 * BM * BK * 2 + 640];   // 32 KB + epilogue
    unsigned short* sA = (unsigned short*)smem;
    unsigned short* sB = (unsigned short*)smem + BM * BK;
    const int tid = threadIdx.x, wave = tid >> 6, lane = tid & 63;
    const int quad = lane >> 4, l16 = lane & 15;
    const int m0 = blockIdx.x * BM, n0 = blockIdx.y * BN;
    const int wm = (wave >> 1) * 64, wn = (wave & 1) * 64;
    const int rsel = lane >> 3, csel = (lane & 7) * 8;
    const int kbeg = blockIdx.z ? 512 : 0;
    const int kend = blockIdx.z ? KTG : 512;

    f32x4 acc[4][4];
    #pragma unroll
    for (int i = 0; i < 4; ++i)
        #pragma unroll
        for (int j = 0; j < 4; ++j) acc[i][j] = (f32x4)0.0f;

    for (int k0 = kbeg; k0 < kend; k0 += BK) {
        __syncthreads();
        #pragma unroll
        for (int j = 0; j < 4; ++j) {
            const int row = wave * 32 + j * 8;
            gload_lds16(A + (size_t)(m0 + row + rsel) * XROW + k0 + csel, &sA[row * BK]);
            gload_lds16(B + (size_t)(n0 + row + rsel) * MROW + k0 + csel, &sB[row * BK]);
        }
        __syncthreads();
        #pragma unroll
        for (int ks = 0; ks < 2; ++ks) {
            const int kc = ks * 32 + quad * 8;
            short8 af[4], bfr[4];
            #pragma unroll
            for (int tt = 0; tt < 4; ++tt)
                af[tt] = *(const short8*)&sA[(wm + tt * 16 + l16) * BK + kc];
            #pragma unroll
            for (int tt = 0; tt < 4; ++tt)
                bfr[tt] = *(const short8*)&sB[(wn + tt * 16 + l16) * BK + kc];
            #pragma unroll
            for (int mt = 0; mt < 4; ++mt)
                #pragma unroll
                for (int nt = 0; nt < 4; ++nt)
                    acc[mt][nt] = __builtin_amdgcn_mfma_f32_16x16x32_bf16(
                        af[mt], bfr[nt], acc[mt][nt], 0, 0, 0);
        }
    }

    // stage P patch (128x128 bf16 = 32 KB), per-row dot-reduce into rsum
    __syncthreads();
    unsigned short* sPp = (unsigned short*)smem;
    #pragma unroll
    for (int j = 0; j < 8; ++j) {
        const int row = wave * 32 + j * 4;
        gload_lds16(P + (size_t)(m0 + row + quad) * DIM + n0 + l16 * 8,
                    &sPp[row * 128]);
    }
    __syncthreads();
    #pragma unroll
    for (int mt = 0; mt < 4; ++mt) {
        #pragma unroll
        for (int r = 0; r < 4; ++r) {
            const int lrow = wm + mt * 16 + quad * 4 + r;
            float v = 0.f;
            #pragma unroll
            for (int nt = 0; nt < 4; ++nt)
                v += acc[mt][nt][r] * bf2f(sPp[lrow * 128 + wn + nt * 16 + l16]);
            v += __shfl_xor(v, 1, 64); v += __shfl_xor(v, 2, 64);
            v += __shfl_xor(v, 4, 64); v += __shfl_xor(v, 8, 64);
            if (l16 == 0) atomicAdd(&rsum[m0 + lrow], v);
        }
    }

    // last-finisher writeout for this 128-row group (16 contributors: 8 y x 2 z)
    __threadfence();
    __syncthreads();
    float* srow  = (float*)(smem + 2 * BM * BK * 2);
    int*   sflag = (int*)(smem + 2 * BM * BK * 2 + 512);
    if (tid == 0) sflag[0] = atomicAdd(&cnt[blockIdx.x], 1);
    __syncthreads();
    if (sflag[0] != 15) return;
    const float c0 = c_slot[0];
    if (tid < 128) {
        float rv = atomicAdd(&rsum[m0 + tid], 0.0f);   // coherent read
        srow[tid] = rv + (float)(m0 + tid) * (g2[m0 + tid] + c0);
    }
    __syncthreads();
    #pragma unroll 4
    for (int r = 0; r < 128; ++r) {
        f32x4 o = (f32x4)srow[r];
        *(f32x4*)&out[(size_t)(m0 + r) * DIM + tid * 4] = o;
    }
}

// ---------------------------------------------------------------- launch
extern "C" void kernel_launch(void* const* d_in, const int* in_sizes, int n_in,
                              void* d_out, int out_size, void* d_ws, size_t ws_size,
                              hipStream_t stream)
{
    const float* x  = (const float*)d_in[0];
    const float* Wk = (const float*)d_in[1];
    const float* bk = (const float*)d_in[2];
    const float* Wq = (const float*)d_in[5];
    const float* bq = (const float*)d_in[6];
    float* out = (float*)d_out;

    // layout (byte offsets, non-overlapping):
    //   xb @0 (17 MiB)  P @17 MiB (16 MiB)  Mt @33 MiB (2.25 MiB)
    //   WqTb @36 MiB (2.25 MiB)  WkTb @39 MiB (2 MiB)  csums @42 MiB (1 MiB)
    //   rsum @43 MiB (32K)  g2 @+32K (32K)  u @+64K (4K)  c @+68K  cnt @+72K
    char* ws = (char*)d_ws;
    const size_t MiB = 1048576;
    unsigned short* xb   = (unsigned short*)(ws);
    unsigned short* P    = (unsigned short*)(ws + 17 * MiB);
    unsigned short* Mt   = (unsigned short*)(ws + 33 * MiB);
    unsigned short* WqTb = (unsigned short*)(ws + 36 * MiB);
    unsigned short* WkTb = (unsigned short*)(ws + 39 * MiB);
    float* csums         = (float*)(ws + 42 * MiB);
    float* rsum          = (float*)(ws + 43 * MiB);
    float* g2            = (float*)(ws + 43 * MiB + 32768);
    float* u             = (float*)(ws + 43 * MiB + 65536);
    float* c_slot        = (float*)(ws + 43 * MiB + 69632);
    int*   cnt           = (int*)  (ws + 43 * MiB + 73728);

    prep<<<1053, 256, 0, stream>>>(Wq, bq, Wk, bk, x, WqTb, WkTb, csums, rsum,
                                   u, c_slot, cnt);
    scan_mgemm<<<584, 256, 0, stream>>>(x, csums, u, xb, P, g2, WkTb, WqTb, Mt);
    tgemm_red<<<dim3(64, 8, 2), 256, 0, stream>>>(xb, Mt, P, rsum, g2, c_slot,
                                                  cnt, out);
}

// Round 7
// 216.415 us; speedup vs baseline: 1.2543x; 1.2543x over previous
//
#include <hip/hip_runtime.h>
#include <hip/hip_bf16.h>

typedef __attribute__((ext_vector_type(8))) short short8;
typedef __attribute__((ext_vector_type(4))) float f32x4;

#define NROWS 8192
#define DIM   1024
#define NCH   256
#define CHROW 32        // rows per chunk
#define XROW  1024      // xb row stride (pure bf16 x, no aug col)
#define MROW  1024      // Mt row stride
#define BM 128
#define BN 128
#define BK 64

__device__ __forceinline__ float bf2f(unsigned short u) {
    union { unsigned int i; float f; } v; v.i = ((unsigned int)u) << 16; return v.f;
}
__device__ __forceinline__ unsigned short f2bf(float f) {
    union { float f; unsigned int i; } v; v.f = f;
    unsigned int r = v.i + 0x7fffu + ((v.i >> 16) & 1u);
    return (unsigned short)(r >> 16);
}
__device__ __forceinline__ void gload_lds16(const unsigned short* g, unsigned short* l) {
    __builtin_amdgcn_global_load_lds(
        (const __attribute__((address_space(1))) void*)g,
        (__attribute__((address_space(3))) void*)l, 16, 0, 0);
}

// ---------------------------------------------------------------- K1: prep
// [0,512)     : 64x64 transpose tiles fp32->bf16 (Wq->WqTb, Wk->WkTb)
// [512,520)   : WqTb augmentation rows 1024..1151 (row 1024 = bq, rest 0)
// [520,1032)  : per-chunk column sums of x -> csums (chunk x col-half)
// [1032,1048) : zero rsum(8192 f) + g2(8192 f) (contiguous)
// [1048,1052) : u[a] = sum_h Wq[h][a]*bk[h]  (fp32)
// [1052]      : c = bq.bk
__global__ __launch_bounds__(256) void prep(
    const float* __restrict__ Wq, const float* __restrict__ bq,
    const float* __restrict__ Wk, const float* __restrict__ bk,
    const float* __restrict__ x,
    unsigned short* __restrict__ WqTb, unsigned short* __restrict__ WkTb,
    float* __restrict__ csums, float* __restrict__ rsum,
    float* __restrict__ u, float* __restrict__ c_slot)
{
    __shared__ float sTf[64 * 65];
    const int bid = blockIdx.x, t = threadIdx.x;
    if (bid < 512) {
        const int mat = bid >> 8, t16 = bid & 255;
        const int h0 = (t16 >> 4) * 64, a0 = (t16 & 15) * 64;
        const float* src = mat ? Wk : Wq;
        unsigned short* dst = mat ? WkTb : WqTb;
        #pragma unroll
        for (int i = 0; i < 4; ++i) {
            int g = i * 256 + t;
            int row = g >> 4, c4 = (g & 15) * 4;
            float4 v = *(const float4*)(src + (size_t)(h0 + row) * DIM + a0 + c4);
            sTf[row * 65 + c4 + 0] = v.x; sTf[row * 65 + c4 + 1] = v.y;
            sTf[row * 65 + c4 + 2] = v.z; sTf[row * 65 + c4 + 3] = v.w;
        }
        __syncthreads();
        #pragma unroll
        for (int i = 0; i < 4; ++i) {
            int g = i * 256 + t;
            int arow = g >> 4, h4 = (g & 15) * 4;
            ushort4 o;
            o.x = f2bf(sTf[(h4 + 0) * 65 + arow]);
            o.y = f2bf(sTf[(h4 + 1) * 65 + arow]);
            o.z = f2bf(sTf[(h4 + 2) * 65 + arow]);
            o.w = f2bf(sTf[(h4 + 3) * 65 + arow]);
            *(ushort4*)(dst + (size_t)(a0 + arow) * DIM + h0 + h4) = o;
        }
    } else if (bid < 520) {
        const int seg = bid - 512;
        const int r0 = 1024 + seg * 16;
        #pragma unroll
        for (int i = 0; i < 16; ++i) {
            int g = i * 256 + t;
            int row = r0 + (g >> 8), c4 = (g & 255) * 4;
            ushort4 o;
            if (row == 1024) {
                o.x = f2bf(bq[c4 + 0]); o.y = f2bf(bq[c4 + 1]);
                o.z = f2bf(bq[c4 + 2]); o.w = f2bf(bq[c4 + 3]);
            } else { o.x = o.y = o.z = o.w = 0; }
            *(ushort4*)(WqTb + (size_t)row * DIM + c4) = o;
        }
    } else if (bid < 1032) {
        const int s = bid - 520, ch = s >> 1, half = s & 1;
        const int col = half * 512 + t * 2;
        float s0 = 0.f, s1 = 0.f;
        #pragma unroll
        for (int r = 0; r < CHROW; ++r) {
            float2 v = *(const float2*)(x + (size_t)(ch * CHROW + r) * DIM + col);
            s0 += v.x; s1 += v.y;
        }
        float2 o; o.x = s0; o.y = s1;
        *(float2*)&csums[(size_t)ch * DIM + col] = o;
    } else if (bid < 1048) {
        const int idx = bid - 1032;             // zero rsum+g2 (16384 floats)
        f32x4 z = (f32x4)0.0f;
        *(f32x4*)&rsum[(idx * 256 + t) * 4] = z;
    } else if (bid < 1052) {
        const int a = (bid - 1048) * 256 + t;
        float s = 0.f;
        #pragma unroll 8
        for (int h = 0; h < DIM; ++h) s += Wq[(size_t)h * DIM + a] * bk[h];
        u[a] = s;
    } else {
        float s = 0.f;
        for (int h = t; h < DIM; h += 256) s += bq[h] * bk[h];
        #pragma unroll
        for (int sh = 32; sh >= 1; sh >>= 1) s += __shfl_xor(s, sh, 64);
        __shared__ float red[4];
        if ((t & 63) == 0) red[t >> 6] = s;
        __syncthreads();
        if (t == 0) c_slot[0] = red[0] + red[1] + red[2] + red[3];
    }
}

// ---------------------------------------------------------------- K2: scan + g2-dot + mgemm
// [0,512)   : per-chunk scan (self-computed exclusive prefix over csums);
//             writes xb (bf16) and P (bf16); atomicAdd g2[row] += x_row.u
// [512,584) : mgemm — Mt[m][n] = sum_h WkT[m][h]*WqTaug[n][h]
//             by<8: bf16 Mt (1024x1024); by==8: only n==1024 -> mcol[m] fp32
__global__ __launch_bounds__(256) void scan_mgemm(
    const float* __restrict__ x, const float* __restrict__ csums,
    const float* __restrict__ u,
    unsigned short* __restrict__ xb, unsigned short* __restrict__ P,
    float* __restrict__ g2,
    const unsigned short* __restrict__ WkTb, const unsigned short* __restrict__ WqTb,
    unsigned short* __restrict__ Mt, float* __restrict__ mcol)
{
    __shared__ __align__(16) char smem[2 * BM * BK * 2];   // 32 KB, dual-use
    const int t = threadIdx.x;
    if (blockIdx.x < 512) {
        const int s = blockIdx.x, ch = s >> 1, half = s & 1;
        const int col = half * 512 + t * 2;
        float2 run; run.x = 0.f; run.y = 0.f;
        #pragma unroll 8
        for (int c2 = 0; c2 < ch; ++c2) {
            float2 v = *(const float2*)&csums[(size_t)c2 * DIM + col];
            run.x += v.x; run.y += v.y;
        }
        const float u0 = u[col], u1 = u[col + 1];
        float part[CHROW];
        #pragma unroll
        for (int r = 0; r < CHROW; ++r) {
            size_t row = (size_t)ch * CHROW + r;
            float2 xv = *(const float2*)(x + row * DIM + col);
            ushort2 pb; pb.x = f2bf(run.x); pb.y = f2bf(run.y);
            *(ushort2*)(P + row * DIM + col) = pb;
            ushort2 xo; xo.x = f2bf(xv.x); xo.y = f2bf(xv.y);
            *(ushort2*)(xb + row * XROW + col) = xo;
            part[r] = xv.x * u0 + xv.y * u1;
            run.x += xv.x; run.y += xv.y;
        }
        float* sP = (float*)smem;
        #pragma unroll
        for (int r = 0; r < CHROW; ++r) sP[r * 256 + t] = part[r];
        __syncthreads();
        const int wave = t >> 6, lane = t & 63;
        #pragma unroll
        for (int r8 = 0; r8 < 8; ++r8) {
            int r = wave * 8 + r8;
            float v = sP[r * 256 + lane]       + sP[r * 256 + 64 + lane]
                    + sP[r * 256 + 128 + lane] + sP[r * 256 + 192 + lane];
            #pragma unroll
            for (int sh = 32; sh >= 1; sh >>= 1) v += __shfl_xor(v, sh, 64);
            if (lane == 0) atomicAdd(&g2[ch * CHROW + r], v);
        }
    } else {
        unsigned short* sA = (unsigned short*)smem;
        unsigned short* sB = (unsigned short*)smem + BM * BK;
        const int s = blockIdx.x - 512;            // 0..71
        const int bx = s & 7, by = s >> 3;         // bx: m over 1024, by: n over 1152
        const int wave = t >> 6, lane = t & 63;
        const int quad = lane >> 4, l16 = lane & 15;
        const int m0 = bx * BM, n0 = by * BN;
        const int wm = (wave >> 1) * 64, wn = (wave & 1) * 64;
        const int rsel = lane >> 3, csel = (lane & 7) * 8;

        f32x4 acc[4][4];
        #pragma unroll
        for (int i = 0; i < 4; ++i)
            #pragma unroll
            for (int j = 0; j < 4; ++j) acc[i][j] = (f32x4)0.0f;

        for (int k0 = 0; k0 < DIM; k0 += BK) {
            __syncthreads();
            #pragma unroll
            for (int j = 0; j < 4; ++j) {
                const int row = wave * 32 + j * 8;
                gload_lds16(WkTb + (size_t)(m0 + row + rsel) * DIM + k0 + csel, &sA[row * BK]);
                gload_lds16(WqTb + (size_t)(n0 + row + rsel) * DIM + k0 + csel, &sB[row * BK]);
            }
            __syncthreads();
            #pragma unroll
            for (int ks = 0; ks < 2; ++ks) {
                const int kc = ks * 32 + quad * 8;
                short8 af[4], bfr[4];
                #pragma unroll
                for (int tt = 0; tt < 4; ++tt)
                    af[tt] = *(const short8*)&sA[(wm + tt * 16 + l16) * BK + kc];
                #pragma unroll
                for (int tt = 0; tt < 4; ++tt)
                    bfr[tt] = *(const short8*)&sB[(wn + tt * 16 + l16) * BK + kc];
                #pragma unroll
                for (int mt = 0; mt < 4; ++mt)
                    #pragma unroll
                    for (int nt = 0; nt < 4; ++nt)
                        acc[mt][nt] = __builtin_amdgcn_mfma_f32_16x16x32_bf16(
                            af[mt], bfr[nt], acc[mt][nt], 0, 0, 0);
            }
        }
        if (by < 8) {
            #pragma unroll
            for (int nt = 0; nt < 4; ++nt) {
                int n = n0 + wn + nt * 16 + l16;
                #pragma unroll
                for (int mt = 0; mt < 4; ++mt)
                    #pragma unroll
                    for (int r = 0; r < 4; ++r) {
                        int m = m0 + wm + mt * 16 + quad * 4 + r;
                        Mt[(size_t)m * MROW + n] = f2bf(acc[mt][nt][r]);
                    }
            }
        } else if (wn == 0 && l16 == 0) {
            // only n == 1024 kept, as fp32
            #pragma unroll
            for (int mt = 0; mt < 4; ++mt)
                #pragma unroll
                for (int r = 0; r < 4; ++r)
                    mcol[m0 + wm + mt * 16 + quad * 4 + r] = acc[mt][0][r];
        }
    }
}

// ---------------------------------------------------------------- K3: tgemm + fused dot-reduce
// T[i][n] = sum_k xb[i][k]*Mt[n][k] + mcol[n] (never materialized);
// atomicAdd rsum[i] += sum_n T[i][n]*P[i][n].  grid (64, 8, 4) split-K.
// mcol term added by z==0 only.
__global__ __launch_bounds__(256) void tgemm_red(
    const unsigned short* __restrict__ A,   // xb 8192 x 1024
    const unsigned short* __restrict__ B,   // Mt 1024 x 1024
    const unsigned short* __restrict__ P,   // 8192 x 1024
    const float* __restrict__ mcol,
    float* __restrict__ rsum)
{
    __shared__ __align__(16) char smem[2 * BM * BK * 2];   // 32 KB; reused for P patch
    unsigned short* sA = (unsigned short*)smem;
    unsigned short* sB = (unsigned short*)smem + BM * BK;
    const int tid = threadIdx.x, wave = tid >> 6, lane = tid & 63;
    const int quad = lane >> 4, l16 = lane & 15;
    const int m0 = blockIdx.x * BM, n0 = blockIdx.y * BN;
    const int wm = (wave >> 1) * 64, wn = (wave & 1) * 64;
    const int rsel = lane >> 3, csel = (lane & 7) * 8;
    const int kbeg = blockIdx.z * 256;
    const int kend = kbeg + 256;

    f32x4 acc[4][4];
    #pragma unroll
    for (int i = 0; i < 4; ++i)
        #pragma unroll
        for (int j = 0; j < 4; ++j) acc[i][j] = (f32x4)0.0f;

    for (int k0 = kbeg; k0 < kend; k0 += BK) {
        __syncthreads();
        #pragma unroll
        for (int j = 0; j < 4; ++j) {
            const int row = wave * 32 + j * 8;
            gload_lds16(A + (size_t)(m0 + row + rsel) * XROW + k0 + csel, &sA[row * BK]);
            gload_lds16(B + (size_t)(n0 + row + rsel) * MROW + k0 + csel, &sB[row * BK]);
        }
        __syncthreads();
        #pragma unroll
        for (int ks = 0; ks < 2; ++ks) {
            const int kc = ks * 32 + quad * 8;
            short8 af[4], bfr[4];
            #pragma unroll
            for (int tt = 0; tt < 4; ++tt)
                af[tt] = *(const short8*)&sA[(wm + tt * 16 + l16) * BK + kc];
            #pragma unroll
            for (int tt = 0; tt < 4; ++tt)
                bfr[tt] = *(const short8*)&sB[(wn + tt * 16 + l16) * BK + kc];
            #pragma unroll
            for (int mt = 0; mt < 4; ++mt)
                #pragma unroll
                for (int nt = 0; nt < 4; ++nt)
                    acc[mt][nt] = __builtin_amdgcn_mfma_f32_16x16x32_bf16(
                        af[mt], bfr[nt], acc[mt][nt], 0, 0, 0);
        }
    }

    // mcol contribution (z==0 only): T[i][n] += mcol[n], row-independent
    float mc[4];
    const bool addm = (blockIdx.z == 0);
    #pragma unroll
    for (int nt = 0; nt < 4; ++nt)
        mc[nt] = addm ? mcol[n0 + wn + nt * 16 + l16] : 0.0f;

    // stage P patch (128x128 bf16 = 32 KB), per-row dot-reduce into rsum
    __syncthreads();
    unsigned short* sPp = (unsigned short*)smem;
    #pragma unroll
    for (int j = 0; j < 8; ++j) {
        const int row = wave * 32 + j * 4;
        gload_lds16(P + (size_t)(m0 + row + quad) * DIM + n0 + l16 * 8,
                    &sPp[row * 128]);
    }
    __syncthreads();
    #pragma unroll
    for (int mt = 0; mt < 4; ++mt) {
        #pragma unroll
        for (int r = 0; r < 4; ++r) {
            const int lrow = wm + mt * 16 + quad * 4 + r;
            float v = 0.f;
            #pragma unroll
            for (int nt = 0; nt < 4; ++nt)
                v += (acc[mt][nt][r] + mc[nt]) * bf2f(sPp[lrow * 128 + wn + nt * 16 + l16]);
            v += __shfl_xor(v, 1, 64); v += __shfl_xor(v, 2, 64);
            v += __shfl_xor(v, 4, 64); v += __shfl_xor(v, 8, 64);
            if (l16 == 0) atomicAdd(&rsum[m0 + lrow], v);
        }
    }
}

// ---------------------------------------------------------------- K4: writeout
// out[i][:] = rsum[i] + i*(g2[i]+c); one block per row
__global__ __launch_bounds__(256) void writeout(
    const float* __restrict__ rsum, const float* __restrict__ g2,
    const float* __restrict__ c_slot, float* __restrict__ out)
{
    const int row = blockIdx.x, t = threadIdx.x;
    const float v = rsum[row] + (float)row * (g2[row] + c_slot[0]);
    f32x4 o = (f32x4)v;
    *(f32x4*)&out[(size_t)row * DIM + t * 4] = o;
}

// ---------------------------------------------------------------- launch
extern "C" void kernel_launch(void* const* d_in, const int* in_sizes, int n_in,
                              void* d_out, int out_size, void* d_ws, size_t ws_size,
                              hipStream_t stream)
{
    const float* x  = (const float*)d_in[0];
    const float* Wk = (const float*)d_in[1];
    const float* bk = (const float*)d_in[2];
    const float* Wq = (const float*)d_in[5];
    const float* bq = (const float*)d_in[6];
    float* out = (float*)d_out;

    // layout (byte offsets, non-overlapping):
    //   xb @0 (16 MiB)  P @16 MiB (16 MiB)  Mt @32 MiB (2 MiB)
    //   WqTb @35 MiB (2.25 MiB)  WkTb @38 MiB (2 MiB)  csums @41 MiB (1 MiB)
    //   rsum @42 MiB (32K)  g2 @+32K  u @+64K (4K)  c @+68K  mcol @+72K (4K)
    char* ws = (char*)d_ws;
    const size_t MiB = 1048576;
    unsigned short* xb   = (unsigned short*)(ws);
    unsigned short* P    = (unsigned short*)(ws + 16 * MiB);
    unsigned short* Mt   = (unsigned short*)(ws + 32 * MiB);
    unsigned short* WqTb = (unsigned short*)(ws + 35 * MiB);
    unsigned short* WkTb = (unsigned short*)(ws + 38 * MiB);
    float* csums         = (float*)(ws + 41 * MiB);
    float* rsum          = (float*)(ws + 42 * MiB);
    float* g2            = (float*)(ws + 42 * MiB + 32768);
    float* u             = (float*)(ws + 42 * MiB + 65536);
    float* c_slot        = (float*)(ws + 42 * MiB + 69632);
    float* mcol          = (float*)(ws + 42 * MiB + 73728);

    prep<<<1053, 256, 0, stream>>>(Wq, bq, Wk, bk, x, WqTb, WkTb, csums, rsum,
                                   u, c_slot);
    scan_mgemm<<<584, 256, 0, stream>>>(x, csums, u, xb, P, g2, WkTb, WqTb,
                                        Mt, mcol);
    tgemm_red<<<dim3(64, 8, 4), 256, 0, stream>>>(xb, Mt, P, mcol, rsum);
    writeout<<<NROWS, 256, 0, stream>>>(rsum, g2, c_slot, out);
}